// Round 10
// baseline (156.260 us; speedup 1.0000x reference)
//
#include <hip/hip_runtime.h>
#include <hip/hip_bf16.h>

// NormalAttention: B=4, N=1600, C=512, heads=8, dh=64. out = softmax(qk^T/8)@k.
// R10 = R7 LDS-free attn (simple loop — R8/R9 showed explicit pipelining loses)
// + exp2-folded scale + 4-way key split: each wave owns 16 keys x 64 qcols, so
// all 4 waves load disjoint k fragments (block k-traffic halves vs R7).
// kt2_ws repacked as dt-pairs per 16B chunk; k2_ws layout unchanged.

typedef __hip_bfloat16 bf16;
typedef __attribute__((ext_vector_type(8))) short short8;
typedef __attribute__((ext_vector_type(4))) short bfx4;
typedef __attribute__((ext_vector_type(4))) float f32x4;

#define NSP 1600
#define CDIM 512
#define DH 64

__device__ __forceinline__ f32x4 mfma32(short8 a, short8 b, f32x4 c) {
  return __builtin_amdgcn_mfma_f32_16x16x32_bf16(a, b, c, 0, 0, 0);
}

#if __has_builtin(__builtin_amdgcn_mfma_f32_16x16x16bf16_1k)
__device__ __forceinline__ f32x4 mfma_k16(bfx4 a, bfx4 b, f32x4 c) {
  return __builtin_amdgcn_mfma_f32_16x16x16bf16_1k(a, b, c, 0, 0, 0);
}
#else
__device__ __forceinline__ f32x4 mfma_k16(bfx4 a, bfx4 b, f32x4 c) {
  short8 a8 = {a.x, a.y, a.z, a.w, 0, 0, 0, 0};
  short8 b8 = {b.x, b.y, b.z, b.w, 0, 0, 0, 0};
  return __builtin_amdgcn_mfma_f32_16x16x32_bf16(a8, b8, c, 0, 0, 0);
}
#endif

__device__ __forceinline__ short8 cvt8(float4 v0, float4 v1) {
  short8 r; bf16* p = (bf16*)&r;
  p[0] = __float2bfloat16(v0.x); p[1] = __float2bfloat16(v0.y);
  p[2] = __float2bfloat16(v0.z); p[3] = __float2bfloat16(v0.w);
  p[4] = __float2bfloat16(v1.x); p[5] = __float2bfloat16(v1.y);
  p[6] = __float2bfloat16(v1.z); p[7] = __float2bfloat16(v1.w);
  return r;
}

// ---------------------------------------------------------------------------
// cvt: x,w -> bf16 (plain); sin/cos -> (d,n) fp32 transpose.  (R5 verbatim)
// ---------------------------------------------------------------------------
extern "C" __global__ __launch_bounds__(256)
void cvt_kernel(const float* __restrict__ x, const float* __restrict__ w,
                const float* __restrict__ sin_t, const float* __restrict__ cos_t,
                bf16* __restrict__ x_bf, bf16* __restrict__ w_bf,
                float* __restrict__ sinT, float* __restrict__ cosT)
{
  __shared__ float t_lds[64][68];
  const int bid = blockIdx.x, tid = threadIdx.x;
  if (bid < 1600) {
    const size_t i = (size_t)bid * 2048 + tid * 8;
    float4 v0 = *(const float4*)(x + i);
    float4 v1 = *(const float4*)(x + i + 4);
    *(short8*)(x_bf + i) = cvt8(v0, v1);
  } else if (bid < 1856) {
    const size_t i = (size_t)(bid - 1600) * 2048 + tid * 8;
    float4 v0 = *(const float4*)(w + i);
    float4 v1 = *(const float4*)(w + i + 4);
    *(short8*)(w_bf + i) = cvt8(v0, v1);
  } else {
    const int t = bid - 1856;
    const float* src = (t < 25) ? sin_t : cos_t;
    float* dst = (t < 25) ? sinT : cosT;
    const int nt = (t < 25) ? t : t - 25;
    const int r = tid >> 2, c = (tid & 3) * 16;
#pragma unroll
    for (int j = 0; j < 4; ++j)
      *(float4*)&t_lds[r][c + j * 4] =
          *(const float4*)(src + (size_t)(nt * 64 + r) * 64 + c + j * 4);
    __syncthreads();
#pragma unroll
    for (int j4 = 0; j4 < 4; ++j4) {
      float4 o;
      o.x = t_lds[c + j4 * 4 + 0][r];
      o.y = t_lds[c + j4 * 4 + 1][r];
      o.z = t_lds[c + j4 * 4 + 2][r];
      o.w = t_lds[c + j4 * 4 + 3][r];
      *(float4*)(dst + (size_t)r * NSP + nt * 64 + c + j4 * 4) = o;
    }
  }
}

// ---------------------------------------------------------------------------
// proj: 128x128 tile, BK=64 (R5-proven). q scaled by 0.125*log2(e).
// k2_ws (QK A-frags): per (bh,ktile) 512 chunks [w][f][quad][col]:
//   slots j: K[key=w*16+col][d=f*32+quad*8+j]        (unchanged from R7/R8)
// kt2_ws (PK A-frags): per (bh,ktile) 512 chunks [w][p][quad][col]:
//   slots 0..3: K^T[d=(2p)*16+col][key=w*16+quad*4+j]
//   slots 4..7: K^T[d=(2p+1)*16+col][same keys]       (NEW: dt-pair packing)
// ---------------------------------------------------------------------------
extern "C" __global__ __launch_bounds__(256)
void proj_kernel(const bf16* __restrict__ x_bf, const bf16* __restrict__ w_bf,
                 const float* __restrict__ bias, const float* __restrict__ sinT,
                 const float* __restrict__ cosT, bf16* __restrict__ q_ws,
                 bf16* __restrict__ k2_ws, bf16* __restrict__ kt2_ws)
{
  __shared__ __align__(16) char smem[36864];
  bf16 (*x_lds)[72] = (bf16(*)[72])smem;              // [128][72]
  bf16 (*w_lds)[72] = (bf16(*)[72])(smem + 18432);    // [128][72]
  bf16* ep = (bf16*)smem;                             // [128][132] overlay

  const int tid  = threadIdx.x;
  const int wave = tid >> 6;
  const int lane = tid & 63;
  const int col  = lane & 15;
  const int quad = lane >> 4;
  const int wm = wave >> 1, wo = wave & 1;
  const int m0 = blockIdx.x * 128;
  const int o0 = blockIdx.y * 128;

  f32x4 acc[4][4];
#pragma unroll
  for (int i = 0; i < 4; ++i)
#pragma unroll
    for (int j = 0; j < 4; ++j) acc[i][j] = {0.f, 0.f, 0.f, 0.f};

  const int srow = tid >> 1;
  const int sch  = (tid & 1) * 32;

  for (int kt = 0; kt < 8; ++kt) {
    __syncthreads();
    {
      const bf16* xs = x_bf + (size_t)(m0 + srow) * CDIM + kt * 64 + sch;
      const bf16* ws = w_bf + (size_t)(o0 + srow) * CDIM + kt * 64 + sch;
#pragma unroll
      for (int j = 0; j < 4; ++j) {
        *(short8*)&x_lds[srow][sch + j * 8] = *(const short8*)(xs + j * 8);
        *(short8*)&w_lds[srow][sch + j * 8] = *(const short8*)(ws + j * 8);
      }
    }
    __syncthreads();
#pragma unroll
    for (int half = 0; half < 2; ++half) {
      short8 af[4], bfr[4];
#pragma unroll
      for (int mt = 0; mt < 4; ++mt)
        af[mt] = *(short8*)&x_lds[wm * 64 + mt * 16 + col][half * 32 + quad * 8];
#pragma unroll
      for (int ot = 0; ot < 4; ++ot)
        bfr[ot] = *(short8*)&w_lds[wo * 64 + ot * 16 + col][half * 32 + quad * 8];
#pragma unroll
      for (int mt = 0; mt < 4; ++mt)
#pragma unroll
        for (int ot = 0; ot < 4; ++ot)
          acc[mt][ot] = mfma32(af[mt], bfr[ot], acc[mt][ot]);
    }
  }

  // ---- epilogue stage 1: theta_shift -> ep[o_local][m_local] (bf16) ----
  __syncthreads();
  const int b_idx = (m0 + wm * 64) / NSP;
  const int n0w   = m0 + wm * 64 - b_idx * NSP;
  const bool isq  = (o0 < 512);
#pragma unroll
  for (int ot = 0; ot < 4; ++ot) {
    const int o_local = wo * 64 + ot * 16 + col;
    const int o_g = o0 + o_local;
    const float bv = bias[o_g];
    const int d = o_g & 63;
#pragma unroll
    for (int mt = 0; mt < 4; ++mt) {
      const int nl = mt * 16 + quad * 4;
      float t[4], rot[4];
#pragma unroll
      for (int r = 0; r < 4; ++r) t[r] = acc[mt][ot][r] + bv;
#pragma unroll
      for (int r = 0; r < 4; ++r) {
        float tp = __shfl_xor(t[r], 1, 64);
        rot[r] = (lane & 1) ? tp : -tp;
      }
      const float4 c4 = *(const float4*)(cosT + (size_t)d * NSP + n0w + nl);
      const float4 s4 = *(const float4*)(sinT + (size_t)d * NSP + n0w + nl);
      float res[4];
      res[0] = t[0] * c4.x + rot[0] * s4.x;
      res[1] = t[1] * c4.y + rot[1] * s4.y;
      res[2] = t[2] * c4.z + rot[2] * s4.z;
      res[3] = t[3] * c4.w + rot[3] * s4.w;
      if (isq) {
#pragma unroll
        for (int r = 0; r < 4; ++r) res[r] *= 0.1803368801111204f;  // 0.125*log2(e)
      }
      bfx4 pk; bf16* pp = (bf16*)&pk;
#pragma unroll
      for (int r = 0; r < 4; ++r) pp[r] = __float2bfloat16(res[r]);
      *(bfx4*)&ep[o_local * 132 + wm * 64 + nl] = pk;
    }
  }
  __syncthreads();

  // ---- epilogue stage 2: coalesced global stores ----
  if (isq) {   // q_ws (bh,n,d) natural
    const int m_l = tid >> 1, half = tid & 1;
    const int gm = m0 + m_l;
    const int bi = gm / NSP, n = gm - bi * NSP;
    const int h = (o0 >> 6) + half;
    bf16* base = q_ws + ((size_t)(bi * 8 + h) * NSP + n) * 64;
#pragma unroll
    for (int c = 0; c < 8; ++c) {
      short8 v; bf16* vp = (bf16*)&v;
#pragma unroll
      for (int j = 0; j < 8; ++j) vp[j] = ep[(half * 64 + c * 8 + j) * 132 + m_l];
      *(short8*)(base + c * 8) = v;
    }
  } else {
    const int h0 = (o0 - 512) >> 6;
    // k2_ws (unchanged layout; w = kh2*2+ti bits)
#pragma unroll
    for (int it = 0; it < 8; ++it) {
      const int ci = it * 256 + tid;
      const int hh = ci >> 10, T = (ci >> 9) & 1, inner = ci & 511;
      const int ccol = inner & 15, cq = (inner >> 4) & 3;
      const int f = (inner >> 6) & 1, ti = (inner >> 7) & 1, kh2 = (inner >> 8) & 1;
      const int gmb = m0 + T * 64;
      const int bi = gmb / NSP, ktile = (gmb - bi * NSP) >> 6;
      const int m_l = T * 64 + (2 * kh2 + ti) * 16 + ccol;
      const int er0 = hh * 64 + (f * 4 + cq) * 8;
      short8 v; bf16* vp = (bf16*)&v;
#pragma unroll
      for (int j = 0; j < 8; ++j) vp[j] = ep[(er0 + j) * 132 + m_l];
      *(short8*)(k2_ws +
          (((size_t)(bi * 8 + h0 + hh) * 25 + ktile) * 512 + inner) * 8) = v;
    }
    // kt2_ws: NEW dt-pair packing [w][p][quad][col]
#pragma unroll
    for (int it = 0; it < 8; ++it) {
      const int ci = it * 256 + tid;
      const int hh = ci >> 10, T = (ci >> 9) & 1, inner = ci & 511;
      const int ccol = inner & 15, cq = (inner >> 4) & 3;
      const int p = (inner >> 6) & 1, w2 = (inner >> 7) & 3;
      const int gmb = m0 + T * 64;
      const int bi = gmb / NSP, ktile = (gmb - bi * NSP) >> 6;
      const bf16* eplo =
          ep + (hh * 64 + p * 32 + ccol) * 132 + T * 64 + w2 * 16 + cq * 4;
      const bf16* ephi = eplo + 16 * 132;
      short8 v;
      ((bfx4*)&v)[0] = *(const bfx4*)eplo;   // dt = 2p
      ((bfx4*)&v)[1] = *(const bfx4*)ephi;   // dt = 2p+1
      *(short8*)(kt2_ws +
          (((size_t)(bi * 8 + h0 + hh) * 25 + ktile) * 512 + inner) * 8) = v;
    }
  }
}

// ---------------------------------------------------------------------------
// attn: LDS-free K-loop, 4-way key split. grid (25,32), 4 waves: wave w owns
// keys w*16..w*16+15 x all 64 qcols. Simple loop (no explicit pipelining).
// ---------------------------------------------------------------------------
extern "C" __global__ __launch_bounds__(256)
void attn_kernel(const bf16* __restrict__ q_ws, const bf16* __restrict__ k2_ws,
                 const bf16* __restrict__ kt2_ws, float* __restrict__ out)
{
  __shared__ float red[3][64][68];   // 52,224 B: 3 waves x (16 f32x4 + 4 l)

  const int qt = blockIdx.x, bh = blockIdx.y;
  const int b = bh >> 3, h = bh & 7;
  const int tid  = threadIdx.x;
  const int wave = tid >> 6;
  const int lane = tid & 63;
  const int col  = lane & 15;
  const int quad = lane >> 4;

  // loop-invariant Q B-fragments: qb[ct][f] = Q[qrow=qt*64+ct*16+col][d=f*32+quad*8+j]
  short8 qb[4][2];
#pragma unroll
  for (int ct = 0; ct < 4; ++ct) {
    const bf16* qp =
        q_ws + ((size_t)bh * NSP + qt * 64 + ct * 16 + col) * 64;
    qb[ct][0] = *(const short8*)(qp + quad * 8);
    qb[ct][1] = *(const short8*)(qp + 32 + quad * 8);
  }

  f32x4 oacc[4][4];   // [dt][ct]: O^T[d=dt*16+quad*4+r][qcol=ct*16+col]
#pragma unroll
  for (int i = 0; i < 4; ++i)
#pragma unroll
    for (int j = 0; j < 4; ++j) oacc[i][j] = {0.f, 0.f, 0.f, 0.f};
  float l_part[4] = {0.f, 0.f, 0.f, 0.f};

  const bf16* k2b  = k2_ws  + (size_t)bh * 25 * 4096;
  const bf16* kt2b = kt2_ws + (size_t)bh * 25 * 4096;

  for (int kt = 0; kt < 25; ++kt) {
    const bf16* kc  = k2b  + kt * 4096;
    const bf16* kc2 = kt2b + kt * 4096;

    // this wave's 16-key fragments (all distinct across waves)
    short8 kf0 = *(const short8*)(kc  + ((wave * 2 + 0) * 64 + lane) * 8);
    short8 kf1 = *(const short8*)(kc  + ((wave * 2 + 1) * 64 + lane) * 8);
    short8 kt0 = *(const short8*)(kc2 + ((wave * 2 + 0) * 64 + lane) * 8);
    short8 kt1 = *(const short8*)(kc2 + ((wave * 2 + 1) * 64 + lane) * 8);

    // S^T = K @ Q^T : keys w*16+quad*4+r (rows) x qcol ct*16+col
    f32x4 s[4];
#pragma unroll
    for (int ct = 0; ct < 4; ++ct) {
      f32x4 t = {0.f, 0.f, 0.f, 0.f};
      t = mfma32(kf0, qb[ct][0], t);
      t = mfma32(kf1, qb[ct][1], t);
      s[ct] = t;
    }

    // P = 2^s; accumulate l; pack P^T B-frags (C-layout == k16 B-layout)
    bfx4 p4[4];
#pragma unroll
    for (int ct = 0; ct < 4; ++ct) {
#pragma unroll
      for (int r = 0; r < 4; ++r) s[ct][r] = exp2f(s[ct][r]);
      l_part[ct] += s[ct][0] + s[ct][1] + s[ct][2] + s[ct][3];
      bf16* pp = (bf16*)&p4[ct];
#pragma unroll
      for (int r = 0; r < 4; ++r) pp[r] = __float2bfloat16(s[ct][r]);
    }

    // O^T += K^T @ P^T over this wave's 16 keys
    bfx4 a0 = __builtin_shufflevector(kt0, kt0, 0, 1, 2, 3);   // dt=0
    bfx4 a1 = __builtin_shufflevector(kt0, kt0, 4, 5, 6, 7);   // dt=1
    bfx4 a2 = __builtin_shufflevector(kt1, kt1, 0, 1, 2, 3);   // dt=2
    bfx4 a3 = __builtin_shufflevector(kt1, kt1, 4, 5, 6, 7);   // dt=3
#pragma unroll
    for (int ct = 0; ct < 4; ++ct) {
      oacc[0][ct] = mfma_k16(a0, p4[ct], oacc[0][ct]);
      oacc[1][ct] = mfma_k16(a1, p4[ct], oacc[1][ct]);
      oacc[2][ct] = mfma_k16(a2, p4[ct], oacc[2][ct]);
      oacc[3][ct] = mfma_k16(a3, p4[ct], oacc[3][ct]);
    }
  }

  // reduce l over quads (wave's 16 keys; lane holds 4 keys' partials per ct)
#pragma unroll
  for (int ct = 0; ct < 4; ++ct) {
    l_part[ct] += __shfl_xor(l_part[ct], 16, 64);
    l_part[ct] += __shfl_xor(l_part[ct], 32, 64);
  }

  // cross-wave (4-way) reduce via LDS
  if (wave >= 1) {
    float* dst = &red[wave - 1][lane][0];
#pragma unroll
    for (int dt = 0; dt < 4; ++dt)
#pragma unroll
      for (int ct = 0; ct < 4; ++ct)
        *(f32x4*)(dst + (dt * 4 + ct) * 4) = oacc[dt][ct];
#pragma unroll
    for (int ct = 0; ct < 4; ++ct) dst[64 + ct] = l_part[ct];
  }
  __syncthreads();
  if (wave == 0) {
#pragma unroll
    for (int wsrc = 0; wsrc < 3; ++wsrc) {
      const float* srcr = &red[wsrc][lane][0];
#pragma unroll
      for (int dt = 0; dt < 4; ++dt)
#pragma unroll
        for (int ct = 0; ct < 4; ++ct)
          oacc[dt][ct] += *(const f32x4*)(srcr + (dt * 4 + ct) * 4);
#pragma unroll
      for (int ct = 0; ct < 4; ++ct) l_part[ct] += srcr[64 + ct];
    }
#pragma unroll
    for (int ct = 0; ct < 4; ++ct) {
      const float inv = 1.f / l_part[ct];
      const int qrow = qt * 64 + ct * 16 + col;
      float* ob = out + ((size_t)b * NSP + qrow) * CDIM + h * 64;
#pragma unroll
      for (int dt = 0; dt < 4; ++dt) {
        float4 v;
        v.x = oacc[dt][ct][0] * inv; v.y = oacc[dt][ct][1] * inv;
        v.z = oacc[dt][ct][2] * inv; v.w = oacc[dt][ct][3] * inv;
        *(float4*)(ob + dt * 16 + quad * 4) = v;
      }
    }
  }
}

extern "C" void kernel_launch(void* const* d_in, const int* in_sizes, int n_in,
                              void* d_out, int out_size, void* d_ws, size_t ws_size,
                              hipStream_t stream) {
  const float* x     = (const float*)d_in[0];
  const float* sin_t = (const float*)d_in[1];
  const float* cos_t = (const float*)d_in[2];
  const float* w_qkv = (const float*)d_in[3];
  const float* b_qkv = (const float*)d_in[4];
  float* out = (float*)d_out;

  const size_t QK = (size_t)32 * NSP * DH;
  bf16* q_ws   = (bf16*)d_ws;
  bf16* k2_ws  = q_ws + QK;
  bf16* kt2_ws = k2_ws + QK;
  bf16* x_bf   = kt2_ws + QK;
  bf16* w_bf   = x_bf + (size_t)6400 * CDIM;
  float* sinT  = (float*)(w_bf + (size_t)1024 * CDIM);
  float* cosT  = sinT + (size_t)DH * NSP;

  cvt_kernel<<<1906, 256, 0, stream>>>(x, w_qkv, sin_t, cos_t, x_bf, w_bf, sinT, cosT);

  dim3 gproj(50, 8);
  proj_kernel<<<gproj, 256, 0, stream>>>(x_bf, w_bf, b_qkv, sinT, cosT,
                                         q_ws, k2_ws, kt2_ws);

  dim3 gattn(25, 32);
  attn_kernel<<<gattn, 256, 0, stream>>>(q_ws, k2_ws, kt2_ws, out);
}

// Round 11
// 148.513 us; speedup vs baseline: 1.0522x; 1.0522x over previous
//
#include <hip/hip_runtime.h>
#include <hip/hip_bf16.h>

// NormalAttention: B=4, N=1600, C=512, heads=8, dh=64. out = softmax(qk^T/8)@k.
// R11 = R7 LDS-free attn structure (simple loop, proven k2/kt2 layouts, VGPR-
// lean) + exp2-folded q scale (R9 proj) + q-tile 32: grid (50,32)=1600 blocks
// -> 6.25 waves/SIMD (2x R7's occupancy). Each wave: 32 keys x 16 qcols.
// Lesson bank: R8 (dynamic reg idx -> scratch), R9 (manual unroll -> VGPR96),
// R10 (wide key split -> VGPR88+52KB LDS) all lost to occupancy. Add blocks,
// not per-wave state.

typedef __hip_bfloat16 bf16;
typedef __attribute__((ext_vector_type(8))) short short8;
typedef __attribute__((ext_vector_type(4))) short bfx4;
typedef __attribute__((ext_vector_type(4))) float f32x4;

#define NSP 1600
#define CDIM 512
#define DH 64

__device__ __forceinline__ f32x4 mfma32(short8 a, short8 b, f32x4 c) {
  return __builtin_amdgcn_mfma_f32_16x16x32_bf16(a, b, c, 0, 0, 0);
}

#if __has_builtin(__builtin_amdgcn_mfma_f32_16x16x16bf16_1k)
__device__ __forceinline__ f32x4 mfma_k16(bfx4 a, bfx4 b, f32x4 c) {
  return __builtin_amdgcn_mfma_f32_16x16x16bf16_1k(a, b, c, 0, 0, 0);
}
#else
__device__ __forceinline__ f32x4 mfma_k16(bfx4 a, bfx4 b, f32x4 c) {
  short8 a8 = {a.x, a.y, a.z, a.w, 0, 0, 0, 0};
  short8 b8 = {b.x, b.y, b.z, b.w, 0, 0, 0, 0};
  return __builtin_amdgcn_mfma_f32_16x16x32_bf16(a8, b8, c, 0, 0, 0);
}
#endif

__device__ __forceinline__ short8 cvt8(float4 v0, float4 v1) {
  short8 r; bf16* p = (bf16*)&r;
  p[0] = __float2bfloat16(v0.x); p[1] = __float2bfloat16(v0.y);
  p[2] = __float2bfloat16(v0.z); p[3] = __float2bfloat16(v0.w);
  p[4] = __float2bfloat16(v1.x); p[5] = __float2bfloat16(v1.y);
  p[6] = __float2bfloat16(v1.z); p[7] = __float2bfloat16(v1.w);
  return r;
}

// ---------------------------------------------------------------------------
// cvt: x,w -> bf16 (plain); sin/cos -> (d,n) fp32 transpose.  (R5 verbatim)
// ---------------------------------------------------------------------------
extern "C" __global__ __launch_bounds__(256)
void cvt_kernel(const float* __restrict__ x, const float* __restrict__ w,
                const float* __restrict__ sin_t, const float* __restrict__ cos_t,
                bf16* __restrict__ x_bf, bf16* __restrict__ w_bf,
                float* __restrict__ sinT, float* __restrict__ cosT)
{
  __shared__ float t_lds[64][68];
  const int bid = blockIdx.x, tid = threadIdx.x;
  if (bid < 1600) {
    const size_t i = (size_t)bid * 2048 + tid * 8;
    float4 v0 = *(const float4*)(x + i);
    float4 v1 = *(const float4*)(x + i + 4);
    *(short8*)(x_bf + i) = cvt8(v0, v1);
  } else if (bid < 1856) {
    const size_t i = (size_t)(bid - 1600) * 2048 + tid * 8;
    float4 v0 = *(const float4*)(w + i);
    float4 v1 = *(const float4*)(w + i + 4);
    *(short8*)(w_bf + i) = cvt8(v0, v1);
  } else {
    const int t = bid - 1856;
    const float* src = (t < 25) ? sin_t : cos_t;
    float* dst = (t < 25) ? sinT : cosT;
    const int nt = (t < 25) ? t : t - 25;
    const int r = tid >> 2, c = (tid & 3) * 16;
#pragma unroll
    for (int j = 0; j < 4; ++j)
      *(float4*)&t_lds[r][c + j * 4] =
          *(const float4*)(src + (size_t)(nt * 64 + r) * 64 + c + j * 4);
    __syncthreads();
#pragma unroll
    for (int j4 = 0; j4 < 4; ++j4) {
      float4 o;
      o.x = t_lds[c + j4 * 4 + 0][r];
      o.y = t_lds[c + j4 * 4 + 1][r];
      o.z = t_lds[c + j4 * 4 + 2][r];
      o.w = t_lds[c + j4 * 4 + 3][r];
      *(float4*)(dst + (size_t)r * NSP + nt * 64 + c + j4 * 4) = o;
    }
  }
}

// ---------------------------------------------------------------------------
// proj: 128x128 tile, BK=64 (R5-proven). q scaled by 0.125*log2(e).
// k epilogue writes fragment-ordered k2_ws / kt2_ws.  (R9 verbatim)
// ---------------------------------------------------------------------------
extern "C" __global__ __launch_bounds__(256)
void proj_kernel(const bf16* __restrict__ x_bf, const bf16* __restrict__ w_bf,
                 const float* __restrict__ bias, const float* __restrict__ sinT,
                 const float* __restrict__ cosT, bf16* __restrict__ q_ws,
                 bf16* __restrict__ k2_ws, bf16* __restrict__ kt2_ws)
{
  __shared__ __align__(16) char smem[36864];
  bf16 (*x_lds)[72] = (bf16(*)[72])smem;              // [128][72]
  bf16 (*w_lds)[72] = (bf16(*)[72])(smem + 18432);    // [128][72]
  bf16* ep = (bf16*)smem;                             // [128][132] overlay

  const int tid  = threadIdx.x;
  const int wave = tid >> 6;
  const int lane = tid & 63;
  const int col  = lane & 15;
  const int quad = lane >> 4;
  const int wm = wave >> 1, wo = wave & 1;
  const int m0 = blockIdx.x * 128;
  const int o0 = blockIdx.y * 128;

  f32x4 acc[4][4];
#pragma unroll
  for (int i = 0; i < 4; ++i)
#pragma unroll
    for (int j = 0; j < 4; ++j) acc[i][j] = {0.f, 0.f, 0.f, 0.f};

  const int srow = tid >> 1;
  const int sch  = (tid & 1) * 32;

  for (int kt = 0; kt < 8; ++kt) {
    __syncthreads();
    {
      const bf16* xs = x_bf + (size_t)(m0 + srow) * CDIM + kt * 64 + sch;
      const bf16* ws = w_bf + (size_t)(o0 + srow) * CDIM + kt * 64 + sch;
#pragma unroll
      for (int j = 0; j < 4; ++j) {
        *(short8*)&x_lds[srow][sch + j * 8] = *(const short8*)(xs + j * 8);
        *(short8*)&w_lds[srow][sch + j * 8] = *(const short8*)(ws + j * 8);
      }
    }
    __syncthreads();
#pragma unroll
    for (int half = 0; half < 2; ++half) {
      short8 af[4], bfr[4];
#pragma unroll
      for (int mt = 0; mt < 4; ++mt)
        af[mt] = *(short8*)&x_lds[wm * 64 + mt * 16 + col][half * 32 + quad * 8];
#pragma unroll
      for (int ot = 0; ot < 4; ++ot)
        bfr[ot] = *(short8*)&w_lds[wo * 64 + ot * 16 + col][half * 32 + quad * 8];
#pragma unroll
      for (int mt = 0; mt < 4; ++mt)
#pragma unroll
        for (int ot = 0; ot < 4; ++ot)
          acc[mt][ot] = mfma32(af[mt], bfr[ot], acc[mt][ot]);
    }
  }

  // ---- epilogue stage 1: theta_shift -> ep[o_local][m_local] (bf16) ----
  __syncthreads();
  const int b_idx = (m0 + wm * 64) / NSP;
  const int n0w   = m0 + wm * 64 - b_idx * NSP;
  const bool isq  = (o0 < 512);
#pragma unroll
  for (int ot = 0; ot < 4; ++ot) {
    const int o_local = wo * 64 + ot * 16 + col;
    const int o_g = o0 + o_local;
    const float bv = bias[o_g];
    const int d = o_g & 63;
#pragma unroll
    for (int mt = 0; mt < 4; ++mt) {
      const int nl = mt * 16 + quad * 4;
      float t[4], rot[4];
#pragma unroll
      for (int r = 0; r < 4; ++r) t[r] = acc[mt][ot][r] + bv;
#pragma unroll
      for (int r = 0; r < 4; ++r) {
        float tp = __shfl_xor(t[r], 1, 64);
        rot[r] = (lane & 1) ? tp : -tp;
      }
      const float4 c4 = *(const float4*)(cosT + (size_t)d * NSP + n0w + nl);
      const float4 s4 = *(const float4*)(sinT + (size_t)d * NSP + n0w + nl);
      float res[4];
      res[0] = t[0] * c4.x + rot[0] * s4.x;
      res[1] = t[1] * c4.y + rot[1] * s4.y;
      res[2] = t[2] * c4.z + rot[2] * s4.z;
      res[3] = t[3] * c4.w + rot[3] * s4.w;
      if (isq) {
#pragma unroll
        for (int r = 0; r < 4; ++r) res[r] *= 0.1803368801111204f;  // 0.125*log2(e)
      }
      bfx4 pk; bf16* pp = (bf16*)&pk;
#pragma unroll
      for (int r = 0; r < 4; ++r) pp[r] = __float2bfloat16(res[r]);
      *(bfx4*)&ep[o_local * 132 + wm * 64 + nl] = pk;
    }
  }
  __syncthreads();

  // ---- epilogue stage 2: coalesced global stores ----
  if (isq) {   // q_ws (bh,n,d) natural
    const int m_l = tid >> 1, half = tid & 1;
    const int gm = m0 + m_l;
    const int bi = gm / NSP, n = gm - bi * NSP;
    const int h = (o0 >> 6) + half;
    bf16* base = q_ws + ((size_t)(bi * 8 + h) * NSP + n) * 64;
#pragma unroll
    for (int c = 0; c < 8; ++c) {
      short8 v; bf16* vp = (bf16*)&v;
#pragma unroll
      for (int j = 0; j < 8; ++j) vp[j] = ep[(half * 64 + c * 8 + j) * 132 + m_l];
      *(short8*)(base + c * 8) = v;
    }
  } else {
    const int h0 = (o0 - 512) >> 6;
    // k2_ws: per (bh,ktile) 512 chunks [kh][ti][f][quad][col]
#pragma unroll
    for (int it = 0; it < 8; ++it) {
      const int ci = it * 256 + tid;
      const int hh = ci >> 10, T = (ci >> 9) & 1, inner = ci & 511;
      const int ccol = inner & 15, cq = (inner >> 4) & 3;
      const int f = (inner >> 6) & 1, ti = (inner >> 7) & 1, kh2 = (inner >> 8) & 1;
      const int gmb = m0 + T * 64;
      const int bi = gmb / NSP, ktile = (gmb - bi * NSP) >> 6;
      const int m_l = T * 64 + (2 * kh2 + ti) * 16 + ccol;
      const int er0 = hh * 64 + (f * 4 + cq) * 8;
      short8 v; bf16* vp = (bf16*)&v;
#pragma unroll
      for (int j = 0; j < 8; ++j) vp[j] = ep[(er0 + j) * 132 + m_l];
      *(short8*)(k2_ws +
          (((size_t)(bi * 8 + h0 + hh) * 25 + ktile) * 512 + inner) * 8) = v;
    }
    // kt2_ws: per (bh,ktile) 512 chunks [kh][dt][quad][col]
#pragma unroll
    for (int it = 0; it < 8; ++it) {
      const int ci = it * 256 + tid;
      const int hh = ci >> 10, T = (ci >> 9) & 1, inner = ci & 511;
      const int ccol = inner & 15, cq = (inner >> 4) & 3;
      const int dt = (inner >> 6) & 3, kh2 = (inner >> 8) & 1;
      const int gmb = m0 + T * 64;
      const int bi = gmb / NSP, ktile = (gmb - bi * NSP) >> 6;
      const bf16* eprow =
          ep + (hh * 64 + dt * 16 + ccol) * 132 + T * 64 + kh2 * 32 + cq * 4;
      short8 v;
      ((bfx4*)&v)[0] = *(const bfx4*)(eprow);
      ((bfx4*)&v)[1] = *(const bfx4*)(eprow + 16);
      *(short8*)(kt2_ws +
          (((size_t)(bi * 8 + h0 + hh) * 25 + ktile) * 512 + inner) * 8) = v;
    }
  }
}

// ---------------------------------------------------------------------------
// attn: LDS-free K-loop, q-tile 32. grid (50,32), 4 waves: qg=wave&1 (16
// qcols), kh=wave>>1 (32 keys). Same per-iter loads as R7, half the compute
// per wave, 2x the blocks -> 6.25 waves/SIMD.
// ---------------------------------------------------------------------------
extern "C" __global__ __launch_bounds__(256)
void attn_kernel(const bf16* __restrict__ q_ws, const bf16* __restrict__ k2_ws,
                 const bf16* __restrict__ kt2_ws, float* __restrict__ out)
{
  __shared__ float red[2][64][20];   // 10,240 B: waves 2,3 -> waves 0,1

  const int qt = blockIdx.x, bh = blockIdx.y;
  const int b = bh >> 3, h = bh & 7;
  const int tid  = threadIdx.x;
  const int wave = tid >> 6;
  const int lane = tid & 63;
  const int col  = lane & 15;
  const int quad = lane >> 4;
  const int qg = wave & 1, kh = wave >> 1;

  // loop-invariant Q B-fragments (16 qcols per wave)
  short8 qb0, qb1;
  {
    const bf16* qp =
        q_ws + ((size_t)bh * NSP + qt * 32 + qg * 16 + col) * 64;
    qb0 = *(const short8*)(qp + quad * 8);
    qb1 = *(const short8*)(qp + 32 + quad * 8);
  }

  f32x4 oacc[4];   // [dt]: O^T[d=dt*16+quad*4+r][qcol=qg*16+col]
#pragma unroll
  for (int i = 0; i < 4; ++i) oacc[i] = {0.f, 0.f, 0.f, 0.f};
  float l_part = 0.f;

  const bf16* k2b  = k2_ws  + (size_t)bh * 25 * 4096;
  const bf16* kt2b = kt2_ws + (size_t)bh * 25 * 4096;

  for (int kt = 0; kt < 25; ++kt) {
    const bf16* kc  = k2b  + kt * 4096;
    const bf16* kc2 = kt2b + kt * 4096;

    // this wave's 32-key fragments (k2: [kh][ti][f][quad][col])
    short8 kf00 = *(const short8*)(kc + (((kh * 2 + 0) * 2 + 0) * 64 + lane) * 8);
    short8 kf01 = *(const short8*)(kc + (((kh * 2 + 0) * 2 + 1) * 64 + lane) * 8);
    short8 kf10 = *(const short8*)(kc + (((kh * 2 + 1) * 2 + 0) * 64 + lane) * 8);
    short8 kf11 = *(const short8*)(kc + (((kh * 2 + 1) * 2 + 1) * 64 + lane) * 8);
    // PK A-frags (kt2: [kh][dt][quad][col])
    short8 ktf0 = *(const short8*)(kc2 + ((kh * 4 + 0) * 64 + lane) * 8);
    short8 ktf1 = *(const short8*)(kc2 + ((kh * 4 + 1) * 64 + lane) * 8);
    short8 ktf2 = *(const short8*)(kc2 + ((kh * 4 + 2) * 64 + lane) * 8);
    short8 ktf3 = *(const short8*)(kc2 + ((kh * 4 + 3) * 64 + lane) * 8);

    // S^T = K @ Q^T : keys (2kh+ti)*16+col x 16 qcols
    f32x4 s0 = {0.f, 0.f, 0.f, 0.f}, s1 = {0.f, 0.f, 0.f, 0.f};
    s0 = mfma32(kf00, qb0, s0); s0 = mfma32(kf01, qb1, s0);
    s1 = mfma32(kf10, qb0, s1); s1 = mfma32(kf11, qb1, s1);

    // P = 2^s (q pre-scaled by log2e/8); accumulate l; pack P^T B-frags
    bfx4 p0, p1;
    {
      bf16* pp0 = (bf16*)&p0; bf16* pp1 = (bf16*)&p1;
#pragma unroll
      for (int r = 0; r < 4; ++r) {
        s0[r] = exp2f(s0[r]); s1[r] = exp2f(s1[r]);
      }
      l_part += s0[0] + s0[1] + s0[2] + s0[3] + s1[0] + s1[1] + s1[2] + s1[3];
#pragma unroll
      for (int r = 0; r < 4; ++r) {
        pp0[r] = __float2bfloat16(s0[r]);
        pp1[r] = __float2bfloat16(s1[r]);
      }
    }

    // O^T += K^T @ P^T over this wave's 32 keys
    {
      bfx4 a0 = __builtin_shufflevector(ktf0, ktf0, 0, 1, 2, 3);
      bfx4 a0h = __builtin_shufflevector(ktf0, ktf0, 4, 5, 6, 7);
      bfx4 a1 = __builtin_shufflevector(ktf1, ktf1, 0, 1, 2, 3);
      bfx4 a1h = __builtin_shufflevector(ktf1, ktf1, 4, 5, 6, 7);
      bfx4 a2 = __builtin_shufflevector(ktf2, ktf2, 0, 1, 2, 3);
      bfx4 a2h = __builtin_shufflevector(ktf2, ktf2, 4, 5, 6, 7);
      bfx4 a3 = __builtin_shufflevector(ktf3, ktf3, 0, 1, 2, 3);
      bfx4 a3h = __builtin_shufflevector(ktf3, ktf3, 4, 5, 6, 7);
      oacc[0] = mfma_k16(a0,  p0, oacc[0]);
      oacc[0] = mfma_k16(a0h, p1, oacc[0]);
      oacc[1] = mfma_k16(a1,  p0, oacc[1]);
      oacc[1] = mfma_k16(a1h, p1, oacc[1]);
      oacc[2] = mfma_k16(a2,  p0, oacc[2]);
      oacc[2] = mfma_k16(a2h, p1, oacc[2]);
      oacc[3] = mfma_k16(a3,  p0, oacc[3]);
      oacc[3] = mfma_k16(a3h, p1, oacc[3]);
    }
  }

  // reduce l over quads (this wave's 32 keys)
  l_part += __shfl_xor(l_part, 16, 64);
  l_part += __shfl_xor(l_part, 32, 64);

  // cross-wave (kh) reduce via LDS: wave 2->0 (qg0), wave 3->1 (qg1)
  if (wave >= 2) {
    float* dst = &red[wave - 2][lane][0];
#pragma unroll
    for (int dt = 0; dt < 4; ++dt)
      *(f32x4*)(dst + dt * 4) = oacc[dt];
    dst[16] = l_part;
  }
  __syncthreads();
  if (wave < 2) {
    const float* srcr = &red[wave][lane][0];
#pragma unroll
    for (int dt = 0; dt < 4; ++dt)
      oacc[dt] += *(const f32x4*)(srcr + dt * 4);
    const float inv = 1.f / (l_part + srcr[16]);
    const int qrow = qt * 32 + qg * 16 + col;
    float* ob = out + ((size_t)b * NSP + qrow) * CDIM + h * 64;
#pragma unroll
    for (int dt = 0; dt < 4; ++dt) {
      float4 v;
      v.x = oacc[dt][0] * inv; v.y = oacc[dt][1] * inv;
      v.z = oacc[dt][2] * inv; v.w = oacc[dt][3] * inv;
      *(float4*)(ob + dt * 16 + quad * 4) = v;
    }
  }
}

extern "C" void kernel_launch(void* const* d_in, const int* in_sizes, int n_in,
                              void* d_out, int out_size, void* d_ws, size_t ws_size,
                              hipStream_t stream) {
  const float* x     = (const float*)d_in[0];
  const float* sin_t = (const float*)d_in[1];
  const float* cos_t = (const float*)d_in[2];
  const float* w_qkv = (const float*)d_in[3];
  const float* b_qkv = (const float*)d_in[4];
  float* out = (float*)d_out;

  const size_t QK = (size_t)32 * NSP * DH;
  bf16* q_ws   = (bf16*)d_ws;
  bf16* k2_ws  = q_ws + QK;
  bf16* kt2_ws = k2_ws + QK;
  bf16* x_bf   = kt2_ws + QK;
  bf16* w_bf   = x_bf + (size_t)6400 * CDIM;
  float* sinT  = (float*)(w_bf + (size_t)1024 * CDIM);
  float* cosT  = sinT + (size_t)DH * NSP;

  cvt_kernel<<<1906, 256, 0, stream>>>(x, w_qkv, sin_t, cos_t, x_bf, w_bf, sinT, cosT);

  dim3 gproj(50, 8);
  proj_kernel<<<gproj, 256, 0, stream>>>(x_bf, w_bf, b_qkv, sinT, cosT,
                                         q_ws, k2_ws, kt2_ws);

  dim3 gattn(50, 32);
  attn_kernel<<<gattn, 256, 0, stream>>>(q_ws, k2_ws, kt2_ws, out);
}